// Round 1
// 216.733 us; speedup vs baseline: 1.0460x; 1.0460x over previous
//
#include <hip/hip_runtime.h>
#include <stdint.h>

#define AS1 __attribute__((address_space(1)))
#define AS3 __attribute__((address_space(3)))

typedef int v4i __attribute__((ext_vector_type(4)));

// Problem constants (from reference)
constexpr int G = 7, B = 8, M = 512, N = 512, K = 1024;
constexpr int GBn = G * B;                       // 56
// X_ZP = -66, Y_ZP = 160 (hardcoded in reference)
// With y' = y - 128:  sum (x-X)(y-Y) = dot(x,y') - 32*rowsum_x + 66*colsum_y' - 2162688

// ws layout: yt [b][n][k] int8 (y-128), then csp[16][B*N] per-k-tile colsum partials
constexpr size_t YT_BYTES = (size_t)B * N * K;   // 4,194,304
constexpr size_t CSP_CNT  = (size_t)16 * B * N;  // 65,536 ints
constexpr size_t WS_NEEDED = YT_BYTES + CSP_CNT * 4;

// ---------------------------------------------------------------------------
// K1: transpose + pack y:  y[b][k][n] (int32, 0..255)  ->  yt[b][n][k] (int8, y-128)
// plus per-(k-tile, b, n) partial colsums of y' into csp.
// 64x64 tiles through LDS. Grid: (N/64, K/64, B), block 256.
// ---------------------------------------------------------------------------
__global__ __launch_bounds__(256) void transpose_pack_y(const int* __restrict__ y,
                                                        signed char* __restrict__ yt,
                                                        int* __restrict__ csp) {
    __shared__ unsigned char tile[64][80];       // 80 = 5*16: 16B-aligned rows, odd 16-bank phase
    int n0  = blockIdx.x * 64;
    int k0t = blockIdx.y;
    int k0  = k0t * 64;
    int b   = blockIdx.z;
    int t   = threadIdx.x;

    // phase 1: coalesced read along n, pack low bytes (^0x80 == y-128 as i8), 16B to LDS
    int r  = t >> 2;                              // k-local 0..63
    int c0 = (t & 3) * 16;                        // n-local byte offset
    const int* src = y + ((size_t)b * K + k0 + r) * N + n0 + c0;
    uint32_t p[4];
#pragma unroll
    for (int q = 0; q < 4; ++q) {
        int4 v = ((const int4*)src)[q];
        p[q] =  (uint32_t)((v.x & 255) ^ 128)
             | ((uint32_t)((v.y & 255) ^ 128) << 8)
             | ((uint32_t)((v.z & 255) ^ 128) << 16)
             | ((uint32_t)((v.w & 255) ^ 128) << 24);
    }
    *(uint4*)&tile[r][c0] = make_uint4(p[0], p[1], p[2], p[3]);
    __syncthreads();

    // phase 2: gather a column of 16 k-bytes per thread, write 16B contiguous in k
    int nl = t >> 2;                              // n-local 0..63
    int kc = (t & 3) * 16;                        // k-local byte offset
    uint32_t q[4];
    int s = 0;
#pragma unroll
    for (int w = 0; w < 4; ++w) {
        uint32_t b0 = tile[kc + w * 4 + 0][nl];
        uint32_t b1 = tile[kc + w * 4 + 1][nl];
        uint32_t b2 = tile[kc + w * 4 + 2][nl];
        uint32_t b3 = tile[kc + w * 4 + 3][nl];
        s += (int)(signed char)b0 + (int)(signed char)b1
           + (int)(signed char)b2 + (int)(signed char)b3;
        q[w] = b0 | (b1 << 8) | (b2 << 16) | (b3 << 24);
    }
    *(uint4*)(yt + ((size_t)b * N + n0 + nl) * K + k0 + kc) = make_uint4(q[0], q[1], q[2], q[3]);

    // quad-reduce partial colsum (4 threads cover 64 k for one n)
    s += __shfl_xor(s, 1, 64);
    s += __shfl_xor(s, 2, 64);
    if ((t & 3) == 0) csp[(size_t)k0t * (B * N) + b * N + n0 + nl] = s;
}

// ---------------------------------------------------------------------------
// K2 (fused GEMM): block = 128 m x 512 n (full N) for one (gb, mt). 512 threads,
// 8 waves (2m x 4n), each wave 64x128 via 4x8 tiles of mfma_i32_16x16x64_i8.
// A is read from x as int32 ONCE, packed in-register -> swizzled ds_write;
// rowsums accumulate inline. B staged via global_load_lds from yt (pre-swizzled
// source). Double-buffered LDS, ONE barrier per K-step; A(t+1) reg loads and
// B(t+1) global_load_lds issued during MFMA(t) so the barrier vmcnt drain is
// exactly the data we need next (T14 async-split).
// LDS swizzle: physical 16B slot p in each 64B row holds k-chunk p ^ ((row>>1)&3)
// (readers use fk = ((lane>>4) ^ ((fr>>1)&3))*16) -> 2-way bank alias = free.
// Grid: 224 blocks (4 mt x 56 gb), XCD-swizzled (224 % 8 == 0, bijective).
// ---------------------------------------------------------------------------
__global__ __launch_bounds__(512, 2) void gemm_fused(const int* __restrict__ x,
                                                     const signed char* __restrict__ yt,
                                                     const int* __restrict__ csp,
                                                     const float* __restrict__ xsp,
                                                     const float* __restrict__ ysp,
                                                     float* __restrict__ out) {
    __shared__ __align__(16) signed char As[2][128 * 64];   // 16 KiB
    __shared__ __align__(16) signed char Bs[2][512 * 64];   // 64 KiB
    __shared__ int cs_lds[512];
    __shared__ int rs_lds[128];

    int id  = blockIdx.x;
    int swz = (id & 7) * 28 + (id >> 3);          // XCD-contiguous chunks
    int gb  = swz >> 2;                           // 0..55
    int mt  = swz & 3;                            // 0..3
    int b   = gb & 7;

    int tid = threadIdx.x, wave = tid >> 6, lane = tid & 63;

    // block colsums: sum 16 per-k-tile partials for every n (coalesced per kt)
    {
        int s = 0;
        const int* p = csp + b * N + tid;
#pragma unroll
        for (int kt = 0; kt < 16; ++kt) s += p[(size_t)kt * (B * N)];
        cs_lds[tid] = s;
    }

    // A staging: thread t handles row t>>2 (0..127), k-quad t&3 (16 ints)
    int arow = tid >> 2;
    int akq  = tid & 3;
    const int4* Asrc = (const int4*)(x + ((size_t)(gb * M + mt * 128 + arow)) * K) + akq * 4;
    int aoff = arow * 64 + ((akq ^ ((arow >> 1) & 3)) << 4);   // swizzled ds_write addr

    // B staging: per wave, call c stages rows c*128 + wave*16 + (lane>>2)
    int brl    = lane >> 2;
    int bchunk = (lane & 3) ^ ((lane >> 3) & 3);               // pre-swizzled source chunk
    const signed char* Bsrc = yt + ((size_t)b * N) * K;

    // fragment read offsets
    int fr = lane & 15;
    int fk = ((lane >> 4) ^ ((fr >> 1) & 3)) << 4;
    int wm = (wave >> 2) * 64;                    // 0 or 64
    int wn = (wave & 3) * 128;                    // 0,128,256,384

    v4i zero = {0, 0, 0, 0};
    v4i acc[4][8];
#pragma unroll
    for (int i = 0; i < 4; ++i)
#pragma unroll
        for (int j = 0; j < 8; ++j) acc[i][j] = zero;

    int rsum = 0;

    // prologue: A(0) -> regs, B(0) -> Bs[0]
    int4 av[4];
#pragma unroll
    for (int q = 0; q < 4; ++q) av[q] = Asrc[q];
#pragma unroll
    for (int c = 0; c < 4; ++c) {
        __builtin_amdgcn_global_load_lds(
            (const AS1 uint32_t*)(Bsrc + (size_t)(c * 128 + wave * 16 + brl) * K + bchunk * 16),
            (AS3 uint32_t*)(&Bs[0][(c * 128 + wave * 16) * 64]), 16, 0, 0);
    }

#pragma unroll 2
    for (int t = 0; t < 16; ++t) {
        int cur = t & 1;

        // pack A(t) -> LDS, accumulate rowsum
        uint32_t pw[4];
        int s = 0;
#pragma unroll
        for (int q = 0; q < 4; ++q) {
            int4 v = av[q];
            s += v.x + v.y + v.z + v.w;
            pw[q] =  (uint32_t)(v.x & 255)
                 | ((uint32_t)(v.y & 255) << 8)
                 | ((uint32_t)(v.z & 255) << 16)
                 | ((uint32_t)(v.w & 255) << 24);
        }
        rsum += s;
        *(uint4*)(&As[cur][aoff]) = make_uint4(pw[0], pw[1], pw[2], pw[3]);

        __syncthreads();   // drains B(t) gloads + A(t) ds_writes: buf[cur] ready

        v4i af[4], bf[8];
#pragma unroll
        for (int i = 0; i < 4; ++i)
            af[i] = *(const v4i*)(&As[cur][(wm + i * 16 + fr) * 64 + fk]);
#pragma unroll
        for (int j = 0; j < 8; ++j)
            bf[j] = *(const v4i*)(&Bs[cur][(wn + j * 16 + fr) * 64 + fk]);

        // issue next step's loads now; they fly under the MFMAs
        if (t < 15) {
#pragma unroll
            for (int q = 0; q < 4; ++q) av[q] = Asrc[(t + 1) * 16 + q];
#pragma unroll
            for (int c = 0; c < 4; ++c) {
                __builtin_amdgcn_global_load_lds(
                    (const AS1 uint32_t*)(Bsrc + (size_t)(c * 128 + wave * 16 + brl) * K
                                          + (t + 1) * 64 + bchunk * 16),
                    (AS3 uint32_t*)(&Bs[cur ^ 1][(c * 128 + wave * 16) * 64]), 16, 0, 0);
            }
        }

#pragma unroll
        for (int i = 0; i < 4; ++i)
#pragma unroll
            for (int j = 0; j < 8; ++j)
                acc[i][j] = __builtin_amdgcn_mfma_i32_16x16x64_i8(af[i], bf[j], acc[i][j], 0, 0, 0);
        // no second barrier: next step writes the OTHER buffer; the single
        // block-wide barrier above orders read(t-1) < write(t+1).
    }

    // rowsum: quad-reduce (4 threads per row), publish to LDS
    rsum += __shfl_xor(rsum, 1, 64);
    rsum += __shfl_xor(rsum, 2, 64);
    if ((tid & 3) == 0) rs_lds[arow] = rsum;
    __syncthreads();

    // epilogue: C = s * (dot - 32*rowsum_x + 66*colsum_y' - 2162688)
    float sc = xsp[0] * ysp[0];
    int colL = lane & 15;
    int rowQ = (lane >> 4) * 4;
    float* outg = out + (size_t)gb * (M * N) + (size_t)(mt * 128) * N;
#pragma unroll
    for (int i = 0; i < 4; ++i) {
#pragma unroll
        for (int r = 0; r < 4; ++r) {
            int row_l = wm + i * 16 + rowQ + r;
            int rsv = rs_lds[row_l];
#pragma unroll
            for (int j = 0; j < 8; ++j) {
                int col = wn + j * 16 + colL;
                int tv = acc[i][j][r] - 32 * rsv + 66 * cs_lds[col] - 2162688;
                outg[(size_t)row_l * N + col] = sc * (float)tv;
            }
        }
    }
}

// ---------------------------------------------------------------------------
// Fallback (only if ws_size is too small): naive but correct.
// sum (x-X)(y-Y) = dot(x,y) - 160*sum_x + 66*sum_y - 10,813,440
// ---------------------------------------------------------------------------
__global__ __launch_bounds__(256) void naive_kernel(const int* __restrict__ x,
                                                    const int* __restrict__ y,
                                                    const float* __restrict__ xsp,
                                                    const float* __restrict__ ysp,
                                                    float* __restrict__ out) {
    size_t idx = (size_t)blockIdx.x * 256 + threadIdx.x;   // over 14,680,064
    int n  = (int)(idx & 511);
    int m  = (int)((idx >> 9) & 511);
    int gb = (int)(idx >> 18);
    int b  = gb & 7;
    const int* xr = x + ((size_t)gb * M + m) * K;
    const int* yc = y + (size_t)b * K * N + n;
    int dot = 0, sx = 0, sy = 0;
    for (int k = 0; k < K; ++k) {
        int a = xr[k];
        int c = yc[(size_t)k * N];
        dot += a * c; sx += a; sy += c;
    }
    float s = xsp[0] * ysp[0];
    out[idx] = s * (float)(dot - 160 * sx + 66 * sy - 10813440);
}

// ---------------------------------------------------------------------------
extern "C" void kernel_launch(void* const* d_in, const int* in_sizes, int n_in,
                              void* d_out, int out_size, void* d_ws, size_t ws_size,
                              hipStream_t stream) {
    const int*   x  = (const int*)d_in[0];     // [7,8,512,1024] int8 values in int32
    const int*   y  = (const int*)d_in[1];     // [8,1024,512] uint8 values in int32
    const float* xs = (const float*)d_in[2];
    const float* ys = (const float*)d_in[3];
    float* out = (float*)d_out;

    if (ws_size < WS_NEEDED) {
        naive_kernel<<<(14680064 + 255) / 256, 256, 0, stream>>>(x, y, xs, ys, out);
        return;
    }

    char* ws = (char*)d_ws;
    signed char* yt  = (signed char*)ws;
    int*         csp = (int*)(ws + YT_BYTES);

    transpose_pack_y<<<dim3(N / 64, K / 64, B), 256, 0, stream>>>(y, yt, csp);
    gemm_fused<<<dim3(224), 512, 0, stream>>>(x, yt, csp, xs, ys, out);
}